// Round 16
// baseline (3204.444 us; speedup 1.0000x reference)
//
#include <hip/hip_runtime.h>

#define B_ 64
#define T_ 512
#define D_ 1024
#define H_ 1024
#define NG_ 4096   // 4*H

typedef __attribute__((ext_vector_type(8))) short short8v;  // 8 bf16 = 4 VGPR
typedef __attribute__((ext_vector_type(4))) float f32x4;

static __device__ inline unsigned short f2bf(float f) {
  unsigned u = __float_as_uint(f);
  return (unsigned short)((u + 0x7fffu + ((u >> 16) & 1u)) >> 16);
}
static __device__ inline float bf2f(unsigned short s) {
  return __uint_as_float((unsigned)s << 16);
}

// LLC-coherent (cross-XCD) ops: bypass L1/L2 via sc0 sc1.
static __device__ inline float4 llc_load4(const float* p) {
  float4 r;
  asm volatile("global_load_dwordx4 %0, %1, off sc0 sc1" : "=v"(r) : "v"(p));
  return r;
}
static __device__ inline void llc_store1(float* p, float v) {
  asm volatile("global_store_dword %0, %1, off sc0 sc1" :: "v"(p), "v"(v) : "memory");
}
static __device__ inline void llc_store_u16(unsigned short* p, unsigned v) {
  asm volatile("global_store_short %0, %1, off sc0 sc1" :: "v"(p), "v"(v) : "memory");
}
#define VMWAIT(N)                                          \
  asm volatile("s_waitcnt vmcnt(" #N ")" ::: "memory");    \
  __builtin_amdgcn_sched_barrier(0);

// ---------------- helpers for fallback path ----------------
__global__ __launch_bounds__(256) void k_trans_h_fwd(const float* __restrict__ h,
                                                     float* __restrict__ hT) {
  int idx = blockIdx.x * 256 + threadIdx.x;
  int b = idx & 63;
  int k = idx >> 6;
  hT[idx] = h[b * H_ + k];
}
__global__ __launch_bounds__(256) void k_trans_h_back(const float* __restrict__ hT,
                                                      float* __restrict__ h) {
  int idx = blockIdx.x * 256 + threadIdx.x;
  int k = idx & (H_ - 1);
  int b = idx >> 10;
  h[idx] = hT[k * 64 + b];
}

// ---------------- init: h0 -> bf16 A-fragment layout ----------------
__global__ __launch_bounds__(256) void k_init_hfrag(const float* __restrict__ h0,
                                                    unsigned short* __restrict__ hf) {
  const int idx = blockIdx.x * 256 + threadIdx.x;   // 65536
  const int j = idx & 7;
  const int l = (idx >> 3) & 63;
  const int bt = (idx >> 9) & 3;
  const int kt = idx >> 11;
  const int b = bt * 16 + (l & 15);
  const int k = kt * 32 + ((l >> 4) << 3) + j;
  hf[idx] = f2bf(h0[b * H_ + k]);
}

// ---------------- final h from ys[t=511] ----------------
__global__ __launch_bounds__(256) void k_h_final(const float* __restrict__ ys,
                                                 float* __restrict__ h) {
  const int idx = blockIdx.x * 256 + threadIdx.x;   // 65536
  const int b = idx >> 10;
  const int k = idx & 1023;
  h[idx] = ys[(size_t)b * (T_ * H_) + (size_t)(T_ - 1) * H_ + k];
}

// ---------------- prep: Wi -> fragment-ordered bf16 (hi only) ----------------
__global__ __launch_bounds__(256) void k_prep_w(const float* __restrict__ Wi,
                                                short8v* __restrict__ wh) {
  const int idx = blockIdx.x * 256 + threadIdx.x;   // 524288 total
  const int l = idx & 63;
  const int kt = (idx >> 6) & 31;
  const int nt = idx >> 11;
  const int n = nt * 16 + (l & 15);
  const int k = kt * 32 + ((l >> 4) << 3);
  short8v h;
#pragma unroll
  for (int j = 0; j < 8; ++j) h[j] = (short)f2bf(Wi[(size_t)(k + j) * NG_ + n]);
  wh[idx] = h;
}

// ---------------- prep: x chunk -> fragment-ordered bf16 (hi only) ----------------
__global__ __launch_bounds__(256) void k_prep_x(const float* __restrict__ x,
                                                short8v* __restrict__ xh,
                                                int t0) {
  const int idx = blockIdx.x * 256 + threadIdx.x;   // tc*8192
  const int l = idx & 63;
  const int bt = (idx >> 6) & 3;
  const int kt = (idx >> 8) & 31;
  const int tt = idx >> 13;
  const int b = bt * 16 + (l & 15);
  const int k = kt * 32 + ((l >> 4) << 3);
  const float* p = x + ((size_t)b * T_ + (t0 + tt)) * D_ + k;
  const float4 f0 = *(const float4*)p;
  const float4 f1 = *(const float4*)(p + 4);
  const float v[8] = {f0.x, f0.y, f0.z, f0.w, f1.x, f1.y, f1.z, f1.w};
  short8v h;
#pragma unroll
  for (int j = 0; j < 8; ++j) h[j] = (short)f2bf(v[j]);
  xh[idx] = h;
}

// ================= fused persistent kernel (chunk-aware) =================
// 256 blocks x 512 thr. Blocks 0..63: recurrence consumers (16 h-cols each,
// Wh hi-only in LDS). Blocks 64..255: gx GEMM producers (tc*8 jobs).
// bar: arrival[i]=bar[i*32] i<8; done[t]=bar[512+t] (global t).
__global__ __launch_bounds__(512, 2) void k_fused(
    const float* __restrict__ Wh,     // [1024][4096]
    const short8v* __restrict__ xh,   // chunk-local, hi only
    const short8v* __restrict__ wh,   // hi only
    const float* __restrict__ bias,
    float* __restrict__ gx,           // [tc][256][64][16] chunk-local
    unsigned short* __restrict__ hfA, unsigned short* __restrict__ hfB,
    float* __restrict__ c_state,      // [64][1024]
    float* __restrict__ ys,           // [64][512][1024]
    unsigned* __restrict__ bar,
    int t0, int tc) {
  extern __shared__ char smemc[];

  const int tid = threadIdx.x;
  const int l = tid & 63;
  const int w = tid >> 6;
  const int bid = blockIdx.x;
  unsigned* done = bar + 512;

  if (bid >= 64) {
    // ---------------- GEMM producer role (bf16-hi only) ----------------
    const int gi = bid - 64;
    const int oct = gi & 7;
    const int nt0 = oct * 32 + w * 4;
    for (int j = gi; j < tc * 8; j += 192) {
      const int tt = j >> 3;               // chunk-local t
      f32x4 acc[4][4];
#pragma unroll
      for (int i = 0; i < 4; ++i)
#pragma unroll
        for (int q = 0; q < 4; ++q) acc[i][q] = (f32x4){0.f, 0.f, 0.f, 0.f};

#pragma unroll 2
      for (int kt = 0; kt < 32; ++kt) {
        short8v ah[4], bh[4];
#pragma unroll
        for (int bt = 0; bt < 4; ++bt)
          ah[bt] = xh[((size_t)(tt * 32 + kt) * 4 + bt) * 64 + l];
#pragma unroll
        for (int q = 0; q < 4; ++q)
          bh[q] = wh[((size_t)(nt0 + q) * 32 + kt) * 64 + l];
#pragma unroll
        for (int bt = 0; bt < 4; ++bt)
#pragma unroll
          for (int q = 0; q < 4; ++q)
            acc[bt][q] = __builtin_amdgcn_mfma_f32_16x16x32_bf16(ah[bt], bh[q], acc[bt][q], 0, 0, 0);
      }

#pragma unroll
      for (int q = 0; q < 4; ++q) {
        const int n = (nt0 + q) * 16 + (l & 15);
        const int g = n >> 10;
        const int cb = (n & 1023) >> 2;
        const int c = n & 3;
        const float bv = bias[n];
#pragma unroll
        for (int bt = 0; bt < 4; ++bt)
#pragma unroll
          for (int r = 0; r < 4; ++r) {
            const int b = bt * 16 + (l >> 4) * 4 + r;
            llc_store1(gx + (((size_t)tt * 256 + cb) * 64 + b) * 16 + c * 4 + g,
                       acc[bt][q][r] + bv);
          }
      }
      asm volatile("s_waitcnt vmcnt(0)" ::: "memory");
      __syncthreads();
      if (tid == 0)
        __hip_atomic_fetch_add(&done[t0 + tt], 1u, __ATOMIC_RELAXED,
                               __HIP_MEMORY_SCOPE_AGENT);
    }
    return;
  }

  // ---------------- recurrence consumer role (bid < 64, 16 h-cols) ----------------
  short8v* wlds = (short8v*)smemc;                     // [4 ct][32 kt][64] = 128 KB
  float* red = (float*)(wlds + 8192);                  // [8 w][2 ctr][64][4] = 16 KB

  const int bt = w & 3;
  const int kt0 = (w >> 2) * 16;
  const int hbase = bid * 16;

  // stage Wh B-frags hi-only; gate-col gc = hcol_local*4 + g, ct = gc>>4
  for (int idx = tid; idx < 8192; idx += 512) {
    const int ct = idx >> 11;
    const int rem = idx & 2047;
    const int kt = rem >> 6;
    const int ll = rem & 63;
    const int gc = ct * 16 + (ll & 15);
    const int hl = gc >> 2;
    const int g = gc & 3;
    const int kb = kt * 32 + ((ll >> 4) << 3);
    short8v hi;
#pragma unroll
    for (int j = 0; j < 8; ++j)
      hi[j] = (short)f2bf(Wh[(size_t)(kb + j) * NG_ + g * H_ + hbase + hl]);
    wlds[idx] = hi;
  }

  const int eb = tid >> 3;        // output b
  const int c8 = tid & 7;         // low col index
  const int hcolA = hbase + c8;
  const int hcolB = hbase + 8 + c8;
  const size_t sOffA = (((size_t)((hcolA >> 5) * 4 + (eb >> 4)) * 64 +
                         ((((hcolA & 31) >> 3) << 4) | (eb & 15))) * 8 + (hcolA & 7));
  const size_t sOffB = (((size_t)((hcolB >> 5) * 4 + (eb >> 4)) * 64 +
                         ((((hcolB & 31) >> 3) << 4) | (eb & 15))) * 8 + (hcolB & 7));
  const int cbA = bid * 4 + (c8 >> 2);
  const int cbB = bid * 4 + 2 + (c8 >> 2);
  const int goff = (c8 & 3) * 4;           // gxv element base
  const int bt_e = eb >> 4;
  const int r_e = eb & 3;
  const int lbase = ((eb & 15) >> 2) << 4;
  const int coff = (c8 & 3) * 4;
  const int ctr = c8 >> 2;                 // same for rounds A and B

  float c_regA = c_state[eb * H_ + hcolA];
  float c_regB = c_state[eb * H_ + hcolB];

  if (tid == 0) {   // wait for this chunk's first gx slice
    while (__hip_atomic_load(&done[t0], __ATOMIC_RELAXED, __HIP_MEMORY_SCOPE_AGENT) < 8u)
      __builtin_amdgcn_s_sleep(1);
  }
  __syncthreads();

  for (int tt = 0; tt < tc; ++tt) {
    const int t = t0 + tt;
    const unsigned short* __restrict__ hf_in = (t & 1) ? hfB : hfA;
    unsigned short* __restrict__ hf_out = (t & 1) ? hfA : hfB;

    // 18 sc loads: gxvA, gxvB, then 16 A-frags
    float4 gxvA = llc_load4(gx + (((size_t)tt * 256 + cbA) * 64 + eb) * 16 + goff);
    float4 gxvB = llc_load4(gx + (((size_t)tt * 256 + cbB) * 64 + eb) * 16 + goff);
    float4 aq[16];
#pragma unroll
    for (int q = 0; q < 16; ++q)
      aq[q] = llc_load4((const float*)(hf_in + (((size_t)(kt0 + q) * 4 + bt) * 64 + l) * 8));

    f32x4 acc0 = (f32x4){0.f, 0.f, 0.f, 0.f};
    f32x4 acc1 = (f32x4){0.f, 0.f, 0.f, 0.f};
    f32x4 acc2 = (f32x4){0.f, 0.f, 0.f, 0.f};
    f32x4 acc3 = (f32x4){0.f, 0.f, 0.f, 0.f};

#define STEPQ(Q, VM)                                                        \
    { const short8v b0 = wlds[(kt0 + (Q)) * 64 + l];                        \
      const short8v b1 = wlds[2048 + (kt0 + (Q)) * 64 + l];                 \
      const short8v b2 = wlds[4096 + (kt0 + (Q)) * 64 + l];                 \
      const short8v b3 = wlds[6144 + (kt0 + (Q)) * 64 + l];                 \
      VMWAIT(VM)                                                            \
      const short8v av = __builtin_bit_cast(short8v, aq[Q]);                \
      acc0 = __builtin_amdgcn_mfma_f32_16x16x32_bf16(av, b0, acc0, 0, 0, 0); \
      acc1 = __builtin_amdgcn_mfma_f32_16x16x32_bf16(av, b1, acc1, 0, 0, 0); \
      acc2 = __builtin_amdgcn_mfma_f32_16x16x32_bf16(av, b2, acc2, 0, 0, 0); \
      acc3 = __builtin_amdgcn_mfma_f32_16x16x32_bf16(av, b3, acc3, 0, 0, 0); }
    STEPQ(0, 15)  STEPQ(1, 14)  STEPQ(2, 13)  STEPQ(3, 12)
    STEPQ(4, 11)  STEPQ(5, 10)  STEPQ(6, 9)   STEPQ(7, 8)
    STEPQ(8, 7)   STEPQ(9, 6)   STEPQ(10, 5)  STEPQ(11, 4)
    STEPQ(12, 3)  STEPQ(13, 2)  STEPQ(14, 1)  STEPQ(15, 0)
#undef STEPQ

    // ---- round A: ct 0,1 -> cols 0..7 ----
#pragma unroll
    for (int r = 0; r < 4; ++r) {
      red[((w * 2 + 0) * 64 + l) * 4 + r] = acc0[r];
      red[((w * 2 + 1) * 64 + l) * 4 + r] = acc1[r];
    }
    __syncthreads();
    {
      const float* gp = &gxvA.x;
      float v[4];
#pragma unroll
      for (int g = 0; g < 4; ++g) {
        const int lp = lbase | (coff + g);
        v[g] = gp[g] +
               red[(((0 + bt_e) * 2 + ctr) * 64 + lp) * 4 + r_e] +
               red[(((4 + bt_e) * 2 + ctr) * 64 + lp) * 4 + r_e];
      }
      const float si = 1.f / (1.f + expf(-v[0]));
      const float sf = 1.f / (1.f + expf(-v[1]));
      const float gt = tanhf(v[2]);
      const float so = 1.f / (1.f + expf(-v[3]));
      const float cn = sf * c_regA + si * gt;
      const float hn = so * tanhf(cn);
      c_regA = cn;
      llc_store_u16(hf_out + sOffA, (unsigned)f2bf(hn));
      ys[(size_t)eb * (T_ * H_) + (size_t)t * H_ + hcolA] = hn;
    }
    __syncthreads();

    // ---- round B: ct 2,3 -> cols 8..15 ----
#pragma unroll
    for (int r = 0; r < 4; ++r) {
      red[((w * 2 + 0) * 64 + l) * 4 + r] = acc2[r];
      red[((w * 2 + 1) * 64 + l) * 4 + r] = acc3[r];
    }
    __syncthreads();
    {
      const float* gp = &gxvB.x;
      float v[4];
#pragma unroll
      for (int g = 0; g < 4; ++g) {
        const int lp = lbase | (coff + g);
        v[g] = gp[g] +
               red[(((0 + bt_e) * 2 + ctr) * 64 + lp) * 4 + r_e] +
               red[(((4 + bt_e) * 2 + ctr) * 64 + lp) * 4 + r_e];
      }
      const float si = 1.f / (1.f + expf(-v[0]));
      const float sf = 1.f / (1.f + expf(-v[1]));
      const float gt = tanhf(v[2]);
      const float so = 1.f / (1.f + expf(-v[3]));
      const float cn = sf * c_regB + si * gt;
      const float hn = so * tanhf(cn);
      c_regB = cn;
      llc_store_u16(hf_out + sOffB, (unsigned)f2bf(hn));
      ys[(size_t)eb * (T_ * H_) + (size_t)t * H_ + hcolB] = hn;
    }

    // drain h stores to LLC, then flat barrier (64 participants)
    asm volatile("s_waitcnt vmcnt(0)" ::: "memory");
    __syncthreads();
    if (tid == 0) {
      __hip_atomic_fetch_add(&bar[(bid & 7) << 5], 1u,
                             __ATOMIC_RELAXED, __HIP_MEMORY_SCOPE_AGENT);
      const unsigned tgt = 64u * (unsigned)(t + 1);
      unsigned s;
      do {
        s = 0;
#pragma unroll
        for (int i = 0; i < 8; ++i)
          s += __hip_atomic_load(&bar[i << 5], __ATOMIC_RELAXED,
                                 __HIP_MEMORY_SCOPE_AGENT);
        if (s < tgt) __builtin_amdgcn_s_sleep(1);
      } while (s < tgt);
    }
    if (tid == 64 && tt + 1 < tc) {   // parallel: ensure next gx slice published
      while (__hip_atomic_load(&done[t + 1], __ATOMIC_RELAXED,
                               __HIP_MEMORY_SCOPE_AGENT) < 8u)
        __builtin_amdgcn_s_sleep(1);
    }
    __syncthreads();
  }

  c_state[eb * H_ + hcolA] = c_regA;
  c_state[eb * H_ + hcolB] = c_regB;
}

// ---------------- fallback: fused step (tiny ws) ----------------
#define FMA16F(V, W0, W1, W2, W3)               \
  acc[0][0] = fmaf((V), (W0).x, acc[0][0]);     \
  acc[1][0] = fmaf((V), (W0).y, acc[1][0]);     \
  acc[2][0] = fmaf((V), (W0).z, acc[2][0]);     \
  acc[3][0] = fmaf((V), (W0).w, acc[3][0]);     \
  acc[0][1] = fmaf((V), (W1).x, acc[0][1]);     \
  acc[1][1] = fmaf((V), (W1).y, acc[1][1]);     \
  acc[2][1] = fmaf((V), (W1).z, acc[2][1]);     \
  acc[3][1] = fmaf((V), (W1).w, acc[3][1]);     \
  acc[0][2] = fmaf((V), (W2).x, acc[0][2]);     \
  acc[1][2] = fmaf((V), (W2).y, acc[1][2]);     \
  acc[2][2] = fmaf((V), (W2).z, acc[2][2]);     \
  acc[3][2] = fmaf((V), (W2).w, acc[3][2]);     \
  acc[0][3] = fmaf((V), (W3).x, acc[0][3]);     \
  acc[1][3] = fmaf((V), (W3).y, acc[1][3]);     \
  acc[2][3] = fmaf((V), (W3).z, acc[2][3]);     \
  acc[3][3] = fmaf((V), (W3).w, acc[3][3]);

__global__ __launch_bounds__(512, 2) void k_lstm_step_fused(
    const float* __restrict__ xsrc, const float* __restrict__ Wi,
    const float* __restrict__ Wh, const float* __restrict__ bias,
    const float* __restrict__ hT_in, float* __restrict__ hT_out,
    float* __restrict__ c_state, float* __restrict__ ys_t) {
  __shared__ float red[8 * 64 * 17];
  const int tid = threadIdx.x;
  const int lane = tid & 63;
  const int w = tid >> 6;
  const int hbase = blockIdx.x * 4;
  float acc[4][4];
#pragma unroll
  for (int c = 0; c < 4; ++c)
#pragma unroll
    for (int g = 0; g < 4; ++g) acc[c][g] = 0.f;
  const int k0 = w * 128;
#pragma unroll 2
  for (int k = k0; k < k0 + 128; ++k) {
    const float hv = hT_in[k * 64 + lane];
    const float xv = xsrc[(size_t)lane * (T_ * D_) + k];
    const float4 wh0 = *(const float4*)(Wh + (size_t)k * NG_ + 0 * H_ + hbase);
    const float4 wh1 = *(const float4*)(Wh + (size_t)k * NG_ + 1 * H_ + hbase);
    const float4 wh2 = *(const float4*)(Wh + (size_t)k * NG_ + 2 * H_ + hbase);
    const float4 wh3 = *(const float4*)(Wh + (size_t)k * NG_ + 3 * H_ + hbase);
    FMA16F(hv, wh0, wh1, wh2, wh3)
    const float4 wi0 = *(const float4*)(Wi + (size_t)k * NG_ + 0 * H_ + hbase);
    const float4 wi1 = *(const float4*)(Wi + (size_t)k * NG_ + 1 * H_ + hbase);
    const float4 wi2 = *(const float4*)(Wi + (size_t)k * NG_ + 2 * H_ + hbase);
    const float4 wi3 = *(const float4*)(Wi + (size_t)k * NG_ + 3 * H_ + hbase);
    FMA16F(xv, wi0, wi1, wi2, wi3)
  }
#pragma unroll
  for (int c = 0; c < 4; ++c)
#pragma unroll
    for (int g = 0; g < 4; ++g) red[(w * 64 + lane) * 17 + c * 4 + g] = acc[c][g];
  __syncthreads();
  if (tid < 256) {
    const int b = tid >> 2;
    const int c = tid & 3;
    const int h = hbase + c;
    float v[4];
#pragma unroll
    for (int g = 0; g < 4; ++g) {
      float s = bias[g * H_ + h];
#pragma unroll
      for (int ww = 0; ww < 8; ++ww) s += red[(ww * 64 + b) * 17 + c * 4 + g];
      v[g] = s;
    }
    const float cold = c_state[b * H_ + h];
    const float si = 1.f / (1.f + expf(-v[0]));
    const float sf = 1.f / (1.f + expf(-v[1]));
    const float gt = tanhf(v[2]);
    const float so = 1.f / (1.f + expf(-v[3]));
    const float cn = sf * cold + si * gt;
    const float hn = so * tanhf(cn);
    c_state[b * H_ + h] = cn;
    hT_out[h * 64 + b] = hn;
    ys_t[(size_t)b * (T_ * H_) + h] = hn;
  }
}

extern "C" void kernel_launch(void* const* d_in, const int* in_sizes, int n_in,
                              void* d_out, int out_size, void* d_ws, size_t ws_size,
                              hipStream_t stream) {
  const float* c0   = (const float*)d_in[0];
  const float* h0   = (const float*)d_in[1];
  const float* x    = (const float*)d_in[2];
  const float* Wi   = (const float*)d_in[3];
  const float* Wh   = (const float*)d_in[4];
  const float* bias = (const float*)d_in[5];

  float* out     = (float*)d_out;
  float* c_state = out;
  float* h_final = out + B_ * H_;
  float* ys      = out + 2 * B_ * H_;

  const size_t hbytes = (size_t)B_ * H_ * sizeof(float);   // 256 KB
  char* ws = (char*)d_ws;
  unsigned* bar = (unsigned*)ws;                        // 8 KB (cells+done[512])
  char* hbufA = ws + 8192;                              // 256 KB slot
  char* hbufB = hbufA + hbytes;
  const size_t wfrag_n = (size_t)256 * 32 * 64;         // 524288 frags
  short8v* wh = (short8v*)(hbufB + hbytes);             // 8 MB (hi only)
  char* chunkbase = (char*)(wh + wfrag_n);

  const size_t xfrag_t = (size_t)32 * 4 * 64;           // frags per t
  const size_t per_t = xfrag_t * sizeof(short8v) + (size_t)256 * 64 * 16 * sizeof(float);
  const size_t fixed = (size_t)(chunkbase - ws);
  size_t avail = (ws_size > fixed) ? ws_size - fixed : 0;
  int Tc = (int)(avail / per_t);
  if (Tc > T_) Tc = T_;

  hipMemsetAsync(bar, 0, 8192, stream);
  hipMemcpyAsync(c_state, c0, hbytes, hipMemcpyDeviceToDevice, stream);

  if (Tc >= 1) {
    unsigned short* hfA = (unsigned short*)hbufA;
    unsigned short* hfB = (unsigned short*)hbufB;

    k_init_hfrag<<<256, 256, 0, stream>>>(h0, hfA);
    k_prep_w<<<2048, 256, 0, stream>>>(Wi, wh);

    const unsigned smem = 8192 * 16 + 4096 * 4;   // 147456 B (Wh 128K + red 16K)

    for (int t0 = 0; t0 < T_; t0 += Tc) {
      const int tc = (T_ - t0 < Tc) ? (T_ - t0) : Tc;
      short8v* xh = (short8v*)chunkbase;
      float* gxbuf = (float*)(xh + (size_t)tc * xfrag_t);

      k_prep_x<<<tc * 32, 256, 0, stream>>>(x, xh, t0);

      int t0v = t0, tcv = tc;
      void* args[] = {(void*)&Wh,  (void*)&xh,   (void*)&wh,
                      (void*)&bias, (void*)&gxbuf,
                      (void*)&hfA, (void*)&hfB,  (void*)&c_state,
                      (void*)&ys,  (void*)&bar,  (void*)&t0v, (void*)&tcv};
      hipLaunchCooperativeKernel((void*)k_fused, dim3(256), dim3(512), args,
                                 smem, stream);
    }
    k_h_final<<<256, 256, 0, stream>>>(ys, h_final);
  } else {
    float* hA = (float*)hbufA;
    float* hB = (float*)hbufB;
    k_trans_h_fwd<<<B_ * H_ / 256, 256, 0, stream>>>(h0, hA);
    for (int t = 0; t < T_; ++t) {
      const float* hin = (t & 1) ? hB : hA;
      float* hout      = (t & 1) ? hA : hB;
      k_lstm_step_fused<<<256, 512, 0, stream>>>(
          x + (size_t)t * D_, Wi, Wh, bias, hin, hout, c_state,
          ys + (size_t)t * H_);
    }
    k_trans_h_back<<<B_ * H_ / 256, 256, 0, stream>>>(hA, h_final);
  }
}

// Round 17
// 2859.962 us; speedup vs baseline: 1.1204x; 1.1204x over previous
//
#include <hip/hip_runtime.h>

#define B_ 64
#define T_ 512
#define D_ 1024
#define H_ 1024
#define NG_ 4096   // 4*H

typedef __attribute__((ext_vector_type(8))) short short8v;  // 8 bf16 = 4 VGPR
typedef __attribute__((ext_vector_type(4))) float f32x4;

static __device__ inline unsigned short f2bf(float f) {
  unsigned u = __float_as_uint(f);
  return (unsigned short)((u + 0x7fffu + ((u >> 16) & 1u)) >> 16);
}
static __device__ inline float bf2f(unsigned short s) {
  return __uint_as_float((unsigned)s << 16);
}

// fast gate math (native v_exp_f32; limit-safe at +-inf)
static __device__ inline float fsigmoid(float x) {
  return 1.f / (1.f + __expf(-x));
}
static __device__ inline float ftanh(float x) {
  return 2.f / (1.f + __expf(-2.f * x)) - 1.f;
}

// LLC-coherent (cross-XCD) ops: bypass L1/L2 via sc0 sc1.
static __device__ inline float4 llc_load4(const float* p) {
  float4 r;
  asm volatile("global_load_dwordx4 %0, %1, off sc0 sc1" : "=v"(r) : "v"(p));
  return r;
}
static __device__ inline void llc_store1(float* p, float v) {
  asm volatile("global_store_dword %0, %1, off sc0 sc1" :: "v"(p), "v"(v) : "memory");
}
static __device__ inline void llc_store_u16(unsigned short* p, unsigned v) {
  asm volatile("global_store_short %0, %1, off sc0 sc1" :: "v"(p), "v"(v) : "memory");
}
#define VMWAIT(N)                                          \
  asm volatile("s_waitcnt vmcnt(" #N ")" ::: "memory");    \
  __builtin_amdgcn_sched_barrier(0);

// ---------------- helpers for fallback path ----------------
__global__ __launch_bounds__(256) void k_trans_h_fwd(const float* __restrict__ h,
                                                     float* __restrict__ hT) {
  int idx = blockIdx.x * 256 + threadIdx.x;
  int b = idx & 63;
  int k = idx >> 6;
  hT[idx] = h[b * H_ + k];
}
__global__ __launch_bounds__(256) void k_trans_h_back(const float* __restrict__ hT,
                                                      float* __restrict__ h) {
  int idx = blockIdx.x * 256 + threadIdx.x;
  int k = idx & (H_ - 1);
  int b = idx >> 10;
  h[idx] = hT[k * 64 + b];
}

// ---------------- init: h0 -> bf16 A-fragment layout ----------------
__global__ __launch_bounds__(256) void k_init_hfrag(const float* __restrict__ h0,
                                                    unsigned short* __restrict__ hf) {
  const int idx = blockIdx.x * 256 + threadIdx.x;   // 65536
  const int j = idx & 7;
  const int l = (idx >> 3) & 63;
  const int bt = (idx >> 9) & 3;
  const int kt = idx >> 11;
  const int b = bt * 16 + (l & 15);
  const int k = kt * 32 + ((l >> 4) << 3) + j;
  hf[idx] = f2bf(h0[b * H_ + k]);
}

// ---------------- final h from ys[t=511] ----------------
__global__ __launch_bounds__(256) void k_h_final(const float* __restrict__ ys,
                                                 float* __restrict__ h) {
  const int idx = blockIdx.x * 256 + threadIdx.x;   // 65536
  const int b = idx >> 10;
  const int k = idx & 1023;
  h[idx] = ys[(size_t)b * (T_ * H_) + (size_t)(T_ - 1) * H_ + k];
}

// ---------------- prep: Wi -> fragment-ordered bf16 (hi only) ----------------
__global__ __launch_bounds__(256) void k_prep_w(const float* __restrict__ Wi,
                                                short8v* __restrict__ wh) {
  const int idx = blockIdx.x * 256 + threadIdx.x;   // 524288 total
  const int l = idx & 63;
  const int kt = (idx >> 6) & 31;
  const int nt = idx >> 11;
  const int n = nt * 16 + (l & 15);
  const int k = kt * 32 + ((l >> 4) << 3);
  short8v h;
#pragma unroll
  for (int j = 0; j < 8; ++j) h[j] = (short)f2bf(Wi[(size_t)(k + j) * NG_ + n]);
  wh[idx] = h;
}

// ---------------- prep: x chunk -> fragment-ordered bf16 (hi only) ----------------
__global__ __launch_bounds__(256) void k_prep_x(const float* __restrict__ x,
                                                short8v* __restrict__ xh,
                                                int t0) {
  const int idx = blockIdx.x * 256 + threadIdx.x;   // tc*8192
  const int l = idx & 63;
  const int bt = (idx >> 6) & 3;
  const int kt = (idx >> 8) & 31;
  const int tt = idx >> 13;
  const int b = bt * 16 + (l & 15);
  const int k = kt * 32 + ((l >> 4) << 3);
  const float* p = x + ((size_t)b * T_ + (t0 + tt)) * D_ + k;
  const float4 f0 = *(const float4*)p;
  const float4 f1 = *(const float4*)(p + 4);
  const float v[8] = {f0.x, f0.y, f0.z, f0.w, f1.x, f1.y, f1.z, f1.w};
  short8v h;
#pragma unroll
  for (int j = 0; j < 8; ++j) h[j] = (short)f2bf(v[j]);
  xh[idx] = h;
}

// ================= fused persistent kernel (chunk-aware) =================
// 256 blocks x 512 thr. Blocks 0..127: recurrence consumers (8 h-cols each).
// Blocks 128..255: gx GEMM producers (tc*8 jobs, chunk-local gx).
// bar: arrival[i]=bar[i*32] i<8; done[t]=bar[512+t] (global t).
__global__ __launch_bounds__(512, 2) void k_fused(
    const float* __restrict__ Wh,     // [1024][4096]
    const short8v* __restrict__ xh,   // chunk-local, hi only
    const short8v* __restrict__ wh,   // hi only
    const float* __restrict__ bias,
    float* __restrict__ gx,           // [tc][256][64][16] chunk-local
    unsigned short* __restrict__ hfA, unsigned short* __restrict__ hfB,
    float* __restrict__ c_state,      // [64][1024]
    float* __restrict__ ys,           // [64][512][1024]
    unsigned* __restrict__ bar,
    int t0, int tc) {
  extern __shared__ char smemc[];

  const int tid = threadIdx.x;
  const int l = tid & 63;
  const int w = tid >> 6;
  const int bid = blockIdx.x;
  unsigned* done = bar + 512;

  if (bid >= 128) {
    // ---------------- GEMM producer role (bf16-hi only) ----------------
    const int gi = bid - 128;
    const int oct = gi & 7;
    const int nt0 = oct * 32 + w * 4;
    for (int j = gi; j < tc * 8; j += 128) {
      const int tt = j >> 3;               // chunk-local t
      f32x4 acc[4][4];
#pragma unroll
      for (int i = 0; i < 4; ++i)
#pragma unroll
        for (int q = 0; q < 4; ++q) acc[i][q] = (f32x4){0.f, 0.f, 0.f, 0.f};

#pragma unroll 2
      for (int kt = 0; kt < 32; ++kt) {
        short8v ah[4], bh[4];
#pragma unroll
        for (int bt = 0; bt < 4; ++bt)
          ah[bt] = xh[((size_t)(tt * 32 + kt) * 4 + bt) * 64 + l];
#pragma unroll
        for (int q = 0; q < 4; ++q)
          bh[q] = wh[((size_t)(nt0 + q) * 32 + kt) * 64 + l];
#pragma unroll
        for (int bt = 0; bt < 4; ++bt)
#pragma unroll
          for (int q = 0; q < 4; ++q)
            acc[bt][q] = __builtin_amdgcn_mfma_f32_16x16x32_bf16(ah[bt], bh[q], acc[bt][q], 0, 0, 0);
      }

#pragma unroll
      for (int q = 0; q < 4; ++q) {
        const int n = (nt0 + q) * 16 + (l & 15);
        const int g = n >> 10;
        const int cb = (n & 1023) >> 2;
        const int c = n & 3;
        const float bv = bias[n];
#pragma unroll
        for (int bt = 0; bt < 4; ++bt)
#pragma unroll
          for (int r = 0; r < 4; ++r) {
            const int b = bt * 16 + (l >> 4) * 4 + r;
            llc_store1(gx + (((size_t)tt * 256 + cb) * 64 + b) * 16 + c * 4 + g,
                       acc[bt][q][r] + bv);
          }
      }
      asm volatile("s_waitcnt vmcnt(0)" ::: "memory");
      __syncthreads();
      if (tid == 0)
        __hip_atomic_fetch_add(&done[t0 + tt], 1u, __ATOMIC_RELAXED,
                               __HIP_MEMORY_SCOPE_AGENT);
    }
    return;
  }

  // ---------------- recurrence consumer role (bid < 128) ----------------
  short8v* wldsh = (short8v*)smemc;                    // [2][32][64] = 64 KB
  short8v* wldsl = wldsh + 4096;                       // 64 KB
  float* red = (float*)(wldsl + 4096);                 // 16 KB

  const int bt = w & 3;
  const int kt0 = (w >> 2) * 16;
  const int hbase = bid * 8;

  // stage Wh B-frags (2 coltiles x 32 kt), bf16 hi/lo (recurrent path keeps lo)
  for (int idx = tid; idx < 4096; idx += 512) {
    const int ct = idx >> 11;
    const int rem = idx & 2047;
    const int kt = rem >> 6;
    const int ll = rem & 63;
    const int cc = ll & 15;
    const int gc = ct * 16 + cc;
    const int c = gc >> 2, g = gc & 3;
    const int kb = kt * 32 + ((ll >> 4) << 3);
    short8v hi, lo;
#pragma unroll
    for (int j = 0; j < 8; ++j) {
      const float v = Wh[(size_t)(kb + j) * NG_ + g * H_ + hbase + c];
      const unsigned short bh = f2bf(v);
      hi[j] = (short)bh;
      lo[j] = (short)f2bf(v - bf2f(bh));
    }
    wldsh[idx] = hi;
    wldsl[idx] = lo;
  }

  const int eb = tid >> 3;        // output b
  const int c8 = tid & 7;         // output h-col within block
  const int hcol = hbase + c8;
  const size_t sOff = (((size_t)((hcol >> 5) * 4 + (eb >> 4)) * 64 +
                        ((((hcol & 31) >> 3) << 4) | (eb & 15))) * 8 + (hcol & 7));
  const int cbq = bid * 2 + (c8 >> 2);       // gx col-block
  const int ebt = eb >> 4;
  const int erb = eb & 15;
  const int err_ = erb & 3;
  const int elrow = (erb >> 2) << 4;
  const int ect = c8 >> 2;

  float c_reg = c_state[eb * H_ + hcol];

  if (tid == 0) {   // wait for this chunk's first gx slice
    while (__hip_atomic_load(&done[t0], __ATOMIC_RELAXED, __HIP_MEMORY_SCOPE_AGENT) < 8u)
      __builtin_amdgcn_s_sleep(1);
  }
  __syncthreads();

  for (int tt = 0; tt < tc; ++tt) {
    const int t = t0 + tt;
    const unsigned short* __restrict__ hf_in = (t & 1) ? hfB : hfA;
    unsigned short* __restrict__ hf_out = (t & 1) ? hfA : hfB;

    // 17 sc loads: gxv first, then 16 A-frags
    float4 gxv = llc_load4(gx + (((size_t)tt * 256 + cbq) * 64 + eb) * 16 + (c8 & 3) * 4);
    float4 aq[16];
#pragma unroll
    for (int q = 0; q < 16; ++q)
      aq[q] = llc_load4((const float*)(hf_in + (((size_t)(kt0 + q) * 4 + bt) * 64 + l) * 8));

    f32x4 acc0 = (f32x4){0.f, 0.f, 0.f, 0.f};
    f32x4 acc1 = (f32x4){0.f, 0.f, 0.f, 0.f};

#define STEPQ(Q, VM)                                                        \
    { const short8v bh0 = wldsh[(kt0 + (Q)) * 64 + l];                      \
      const short8v bl0 = wldsl[(kt0 + (Q)) * 64 + l];                      \
      const short8v bh1 = wldsh[2048 + (kt0 + (Q)) * 64 + l];               \
      const short8v bl1 = wldsl[2048 + (kt0 + (Q)) * 64 + l];               \
      VMWAIT(VM)                                                            \
      const short8v av = __builtin_bit_cast(short8v, aq[Q]);                \
      acc0 = __builtin_amdgcn_mfma_f32_16x16x32_bf16(av, bh0, acc0, 0, 0, 0); \
      acc0 = __builtin_amdgcn_mfma_f32_16x16x32_bf16(av, bl0, acc0, 0, 0, 0); \
      acc1 = __builtin_amdgcn_mfma_f32_16x16x32_bf16(av, bh1, acc1, 0, 0, 0); \
      acc1 = __builtin_amdgcn_mfma_f32_16x16x32_bf16(av, bl1, acc1, 0, 0, 0); }
    STEPQ(0, 15)  STEPQ(1, 14)  STEPQ(2, 13)  STEPQ(3, 12)
    STEPQ(4, 11)  STEPQ(5, 10)  STEPQ(6, 9)   STEPQ(7, 8)
    STEPQ(8, 7)   STEPQ(9, 6)   STEPQ(10, 5)  STEPQ(11, 4)
    STEPQ(12, 3)  STEPQ(13, 2)  STEPQ(14, 1)  STEPQ(15, 0)
#undef STEPQ

#pragma unroll
    for (int r = 0; r < 4; ++r) {
      red[((w * 2 + 0) * 64 + l) * 4 + r] = acc0[r];
      red[((w * 2 + 1) * 64 + l) * 4 + r] = acc1[r];
    }
    __syncthreads();

    float hn_save;
    {
      const float* gp = &gxv.x;
      float v[4];
#pragma unroll
      for (int g = 0; g < 4; ++g) {
        const int cc = (c8 & 3) * 4 + g;
        const int lp = elrow | cc;
        v[g] = gp[g] +
               red[(((0 * 4 + ebt) * 2 + ect) * 64 + lp) * 4 + err_] +
               red[(((1 * 4 + ebt) * 2 + ect) * 64 + lp) * 4 + err_];
      }
      const float si = fsigmoid(v[0]);
      const float sf = fsigmoid(v[1]);
      const float gt = ftanh(v[2]);
      const float so = fsigmoid(v[3]);
      const float cn = sf * c_reg + si * gt;
      const float hn = so * ftanh(cn);
      c_reg = cn;
      hn_save = hn;
      llc_store_u16(hf_out + sOff, (unsigned)f2bf(hn));   // the only pre-barrier store
    }

    // drain h handoff store, then flat barrier; ys store deferred past arrival
    asm volatile("s_waitcnt vmcnt(0)" ::: "memory");
    __syncthreads();
    if (tid == 0) {
      __hip_atomic_fetch_add(&bar[(bid & 7) << 5], 1u,
                             __ATOMIC_RELAXED, __HIP_MEMORY_SCOPE_AGENT);
    }
    // deferred output store (consumer-private, nothing polls it)
    ys[(size_t)eb * (T_ * H_) + (size_t)t * H_ + hcol] = hn_save;
    if (tid == 0) {
      const unsigned tgt = 128u * (unsigned)(t + 1);
      unsigned s;
      do {
        s = 0;
#pragma unroll
        for (int i = 0; i < 8; ++i)
          s += __hip_atomic_load(&bar[i << 5], __ATOMIC_RELAXED,
                                 __HIP_MEMORY_SCOPE_AGENT);
        if (s < tgt) __builtin_amdgcn_s_sleep(1);
      } while (s < tgt);
    }
    if (tid == 64 && tt + 1 < tc) {   // parallel: ensure next gx slice published
      while (__hip_atomic_load(&done[t + 1], __ATOMIC_RELAXED,
                               __HIP_MEMORY_SCOPE_AGENT) < 8u)
        __builtin_amdgcn_s_sleep(1);
    }
    __syncthreads();
  }

  c_state[eb * H_ + hcol] = c_reg;
}

// ---------------- fallback: fused step (tiny ws) ----------------
#define FMA16F(V, W0, W1, W2, W3)               \
  acc[0][0] = fmaf((V), (W0).x, acc[0][0]);     \
  acc[1][0] = fmaf((V), (W0).y, acc[1][0]);     \
  acc[2][0] = fmaf((V), (W0).z, acc[2][0]);     \
  acc[3][0] = fmaf((V), (W0).w, acc[3][0]);     \
  acc[0][1] = fmaf((V), (W1).x, acc[0][1]);     \
  acc[1][1] = fmaf((V), (W1).y, acc[1][1]);     \
  acc[2][1] = fmaf((V), (W1).z, acc[2][1]);     \
  acc[3][1] = fmaf((V), (W1).w, acc[3][1]);     \
  acc[0][2] = fmaf((V), (W2).x, acc[0][2]);     \
  acc[1][2] = fmaf((V), (W2).y, acc[1][2]);     \
  acc[2][2] = fmaf((V), (W2).z, acc[2][2]);     \
  acc[3][2] = fmaf((V), (W2).w, acc[3][2]);     \
  acc[0][3] = fmaf((V), (W3).x, acc[0][3]);     \
  acc[1][3] = fmaf((V), (W3).y, acc[1][3]);     \
  acc[2][3] = fmaf((V), (W3).z, acc[2][3]);     \
  acc[3][3] = fmaf((V), (W3).w, acc[3][3]);

__global__ __launch_bounds__(512, 2) void k_lstm_step_fused(
    const float* __restrict__ xsrc, const float* __restrict__ Wi,
    const float* __restrict__ Wh, const float* __restrict__ bias,
    const float* __restrict__ hT_in, float* __restrict__ hT_out,
    float* __restrict__ c_state, float* __restrict__ ys_t) {
  __shared__ float red[8 * 64 * 17];
  const int tid = threadIdx.x;
  const int lane = tid & 63;
  const int w = tid >> 6;
  const int hbase = blockIdx.x * 4;
  float acc[4][4];
#pragma unroll
  for (int c = 0; c < 4; ++c)
#pragma unroll
    for (int g = 0; g < 4; ++g) acc[c][g] = 0.f;
  const int k0 = w * 128;
#pragma unroll 2
  for (int k = k0; k < k0 + 128; ++k) {
    const float hv = hT_in[k * 64 + lane];
    const float xv = xsrc[(size_t)lane * (T_ * D_) + k];
    const float4 wh0 = *(const float4*)(Wh + (size_t)k * NG_ + 0 * H_ + hbase);
    const float4 wh1 = *(const float4*)(Wh + (size_t)k * NG_ + 1 * H_ + hbase);
    const float4 wh2 = *(const float4*)(Wh + (size_t)k * NG_ + 2 * H_ + hbase);
    const float4 wh3 = *(const float4*)(Wh + (size_t)k * NG_ + 3 * H_ + hbase);
    FMA16F(hv, wh0, wh1, wh2, wh3)
    const float4 wi0 = *(const float4*)(Wi + (size_t)k * NG_ + 0 * H_ + hbase);
    const float4 wi1 = *(const float4*)(Wi + (size_t)k * NG_ + 1 * H_ + hbase);
    const float4 wi2 = *(const float4*)(Wi + (size_t)k * NG_ + 2 * H_ + hbase);
    const float4 wi3 = *(const float4*)(Wi + (size_t)k * NG_ + 3 * H_ + hbase);
    FMA16F(xv, wi0, wi1, wi2, wi3)
  }
#pragma unroll
  for (int c = 0; c < 4; ++c)
#pragma unroll
    for (int g = 0; g < 4; ++g) red[(w * 64 + lane) * 17 + c * 4 + g] = acc[c][g];
  __syncthreads();
  if (tid < 256) {
    const int b = tid >> 2;
    const int c = tid & 3;
    const int h = hbase + c;
    float v[4];
#pragma unroll
    for (int g = 0; g < 4; ++g) {
      float s = bias[g * H_ + h];
#pragma unroll
      for (int ww = 0; ww < 8; ++ww) s += red[(ww * 64 + b) * 17 + c * 4 + g];
      v[g] = s;
    }
    const float cold = c_state[b * H_ + h];
    const float si = 1.f / (1.f + expf(-v[0]));
    const float sf = 1.f / (1.f + expf(-v[1]));
    const float gt = tanhf(v[2]);
    const float so = 1.f / (1.f + expf(-v[3]));
    const float cn = sf * cold + si * gt;
    const float hn = so * tanhf(cn);
    c_state[b * H_ + h] = cn;
    hT_out[h * 64 + b] = hn;
    ys_t[(size_t)b * (T_ * H_) + h] = hn;
  }
}

extern "C" void kernel_launch(void* const* d_in, const int* in_sizes, int n_in,
                              void* d_out, int out_size, void* d_ws, size_t ws_size,
                              hipStream_t stream) {
  const float* c0   = (const float*)d_in[0];
  const float* h0   = (const float*)d_in[1];
  const float* x    = (const float*)d_in[2];
  const float* Wi   = (const float*)d_in[3];
  const float* Wh   = (const float*)d_in[4];
  const float* bias = (const float*)d_in[5];

  float* out     = (float*)d_out;
  float* c_state = out;
  float* h_final = out + B_ * H_;
  float* ys      = out + 2 * B_ * H_;

  const size_t hbytes = (size_t)B_ * H_ * sizeof(float);   // 256 KB
  char* ws = (char*)d_ws;
  unsigned* bar = (unsigned*)ws;                        // 8 KB (cells+done[512])
  char* hbufA = ws + 8192;                              // 256 KB slot
  char* hbufB = hbufA + hbytes;
  const size_t wfrag_n = (size_t)256 * 32 * 64;         // 524288 frags
  short8v* wh = (short8v*)(hbufB + hbytes);             // 8 MB (hi only)
  char* chunkbase = (char*)(wh + wfrag_n);

  const size_t xfrag_t = (size_t)32 * 4 * 64;           // frags per t
  const size_t per_t = xfrag_t * sizeof(short8v) + (size_t)256 * 64 * 16 * sizeof(float);
  const size_t fixed = (size_t)(chunkbase - ws);
  size_t avail = (ws_size > fixed) ? ws_size - fixed : 0;
  int Tc = (int)(avail / per_t);
  if (Tc > T_) Tc = T_;

  hipMemsetAsync(bar, 0, 8192, stream);
  hipMemcpyAsync(c_state, c0, hbytes, hipMemcpyDeviceToDevice, stream);

  if (Tc >= 1) {
    unsigned short* hfA = (unsigned short*)hbufA;
    unsigned short* hfB = (unsigned short*)hbufB;

    k_init_hfrag<<<256, 256, 0, stream>>>(h0, hfA);
    k_prep_w<<<2048, 256, 0, stream>>>(Wi, wh);

    const unsigned smem = (4096 + 4096) * 16 + 4096 * 4;   // 147456 B

    for (int t0 = 0; t0 < T_; t0 += Tc) {
      const int tc = (T_ - t0 < Tc) ? (T_ - t0) : Tc;
      short8v* xh = (short8v*)chunkbase;
      float* gxbuf = (float*)(xh + (size_t)tc * xfrag_t);

      k_prep_x<<<tc * 32, 256, 0, stream>>>(x, xh, t0);

      int t0v = t0, tcv = tc;
      void* args[] = {(void*)&Wh,  (void*)&xh,   (void*)&wh,
                      (void*)&bias, (void*)&gxbuf,
                      (void*)&hfA, (void*)&hfB,  (void*)&c_state,
                      (void*)&ys,  (void*)&bar,  (void*)&t0v, (void*)&tcv};
      hipLaunchCooperativeKernel((void*)k_fused, dim3(256), dim3(512), args,
                                 smem, stream);
    }
    k_h_final<<<256, 256, 0, stream>>>(ys, h_final);
  } else {
    float* hA = (float*)hbufA;
    float* hB = (float*)hbufB;
    k_trans_h_fwd<<<B_ * H_ / 256, 256, 0, stream>>>(h0, hA);
    for (int t = 0; t < T_; ++t) {
      const float* hin = (t & 1) ? hB : hA;
      float* hout      = (t & 1) ? hA : hB;
      k_lstm_step_fused<<<256, 512, 0, stream>>>(
          x + (size_t)t * D_, Wi, Wh, bias, hin, hout, c_state,
          ys + (size_t)t * H_);
    }
    k_trans_h_back<<<B_ * H_ / 256, 256, 0, stream>>>(hA, h_final);
  }
}

// Round 18
// 2765.453 us; speedup vs baseline: 1.1587x; 1.0342x over previous
//
#include <hip/hip_runtime.h>

#define B_ 64
#define T_ 512
#define D_ 1024
#define H_ 1024
#define NG_ 4096   // 4*H

typedef __attribute__((ext_vector_type(8))) short short8v;  // 8 bf16 = 4 VGPR
typedef __attribute__((ext_vector_type(4))) float f32x4;

static __device__ inline unsigned short f2bf(float f) {
  unsigned u = __float_as_uint(f);
  return (unsigned short)((u + 0x7fffu + ((u >> 16) & 1u)) >> 16);
}
static __device__ inline float bf2f(unsigned short s) {
  return __uint_as_float((unsigned)s << 16);
}

// fast gate math (native v_exp_f32; limit-safe at +-inf)
static __device__ inline float fsigmoid(float x) {
  return 1.f / (1.f + __expf(-x));
}
static __device__ inline float ftanh(float x) {
  return 2.f / (1.f + __expf(-2.f * x)) - 1.f;
}

// LLC-coherent (cross-XCD) ops: bypass L1/L2 via sc0 sc1.
static __device__ inline float4 llc_load4(const float* p) {
  float4 r;
  asm volatile("global_load_dwordx4 %0, %1, off sc0 sc1" : "=v"(r) : "v"(p));
  return r;
}
static __device__ inline void llc_store1(float* p, float v) {
  asm volatile("global_store_dword %0, %1, off sc0 sc1" :: "v"(p), "v"(v) : "memory");
}
static __device__ inline void llc_store_u16(unsigned short* p, unsigned v) {
  asm volatile("global_store_short %0, %1, off sc0 sc1" :: "v"(p), "v"(v) : "memory");
}
#define VMWAIT(N)                                          \
  asm volatile("s_waitcnt vmcnt(" #N ")" ::: "memory");    \
  __builtin_amdgcn_sched_barrier(0);

// ---------------- helpers for fallback path ----------------
__global__ __launch_bounds__(256) void k_trans_h_fwd(const float* __restrict__ h,
                                                     float* __restrict__ hT) {
  int idx = blockIdx.x * 256 + threadIdx.x;
  int b = idx & 63;
  int k = idx >> 6;
  hT[idx] = h[b * H_ + k];
}
__global__ __launch_bounds__(256) void k_trans_h_back(const float* __restrict__ hT,
                                                      float* __restrict__ h) {
  int idx = blockIdx.x * 256 + threadIdx.x;
  int k = idx & (H_ - 1);
  int b = idx >> 10;
  h[idx] = hT[k * 64 + b];
}

// ---------------- init: h0 -> bf16 A-fragment layout ----------------
__global__ __launch_bounds__(256) void k_init_hfrag(const float* __restrict__ h0,
                                                    unsigned short* __restrict__ hf) {
  const int idx = blockIdx.x * 256 + threadIdx.x;   // 65536
  const int j = idx & 7;
  const int l = (idx >> 3) & 63;
  const int bt = (idx >> 9) & 3;
  const int kt = idx >> 11;
  const int b = bt * 16 + (l & 15);
  const int k = kt * 32 + ((l >> 4) << 3) + j;
  hf[idx] = f2bf(h0[b * H_ + k]);
}

// ---------------- final h from ys[t=511] ----------------
__global__ __launch_bounds__(256) void k_h_final(const float* __restrict__ ys,
                                                 float* __restrict__ h) {
  const int idx = blockIdx.x * 256 + threadIdx.x;   // 65536
  const int b = idx >> 10;
  const int k = idx & 1023;
  h[idx] = ys[(size_t)b * (T_ * H_) + (size_t)(T_ - 1) * H_ + k];
}

// ---------------- prep: Wi -> fragment-ordered bf16 (hi only) ----------------
__global__ __launch_bounds__(256) void k_prep_w(const float* __restrict__ Wi,
                                                short8v* __restrict__ wh) {
  const int idx = blockIdx.x * 256 + threadIdx.x;   // 524288 total
  const int l = idx & 63;
  const int kt = (idx >> 6) & 31;
  const int nt = idx >> 11;
  const int n = nt * 16 + (l & 15);
  const int k = kt * 32 + ((l >> 4) << 3);
  short8v h;
#pragma unroll
  for (int j = 0; j < 8; ++j) h[j] = (short)f2bf(Wi[(size_t)(k + j) * NG_ + n]);
  wh[idx] = h;
}

// ---------------- prep: x chunk -> fragment-ordered bf16 (hi only) ----------------
__global__ __launch_bounds__(256) void k_prep_x(const float* __restrict__ x,
                                                short8v* __restrict__ xh,
                                                int t0) {
  const int idx = blockIdx.x * 256 + threadIdx.x;   // tc*8192
  const int l = idx & 63;
  const int bt = (idx >> 6) & 3;
  const int kt = (idx >> 8) & 31;
  const int tt = idx >> 13;
  const int b = bt * 16 + (l & 15);
  const int k = kt * 32 + ((l >> 4) << 3);
  const float* p = x + ((size_t)b * T_ + (t0 + tt)) * D_ + k;
  const float4 f0 = *(const float4*)p;
  const float4 f1 = *(const float4*)(p + 4);
  const float v[8] = {f0.x, f0.y, f0.z, f0.w, f1.x, f1.y, f1.z, f1.w};
  short8v h;
#pragma unroll
  for (int j = 0; j < 8; ++j) h[j] = (short)f2bf(v[j]);
  xh[idx] = h;
}

// ================= fused persistent kernel (chunk-aware) =================
// 256 blocks x 512 thr. Blocks 0..127: recurrence consumers (8 h-cols each).
// Blocks 128..255: gx GEMM producers (tc*8 jobs, chunk-local gx).
// bar: arrival[i]=bar[i*32] i<8; epoch=bar[256]; done[t]=bar[512+t] (global t).
__global__ __launch_bounds__(512, 2) void k_fused(
    const float* __restrict__ Wh,     // [1024][4096]
    const short8v* __restrict__ xh,   // chunk-local, hi only
    const short8v* __restrict__ wh,   // hi only
    const float* __restrict__ bias,
    float* __restrict__ gx,           // [tc][256][64][16] chunk-local
    unsigned short* __restrict__ hfA, unsigned short* __restrict__ hfB,
    float* __restrict__ c_state,      // [64][1024]
    float* __restrict__ ys,           // [64][512][1024]
    unsigned* __restrict__ bar,
    int t0, int tc) {
  extern __shared__ char smemc[];

  const int tid = threadIdx.x;
  const int l = tid & 63;
  const int w = tid >> 6;
  const int bid = blockIdx.x;
  unsigned* done = bar + 512;

  if (bid >= 128) {
    // ---------------- GEMM producer role (bf16-hi only) ----------------
    const int gi = bid - 128;
    const int oct = gi & 7;
    const int nt0 = oct * 32 + w * 4;
    for (int j = gi; j < tc * 8; j += 128) {
      const int tt = j >> 3;               // chunk-local t
      f32x4 acc[4][4];
#pragma unroll
      for (int i = 0; i < 4; ++i)
#pragma unroll
        for (int q = 0; q < 4; ++q) acc[i][q] = (f32x4){0.f, 0.f, 0.f, 0.f};

#pragma unroll 2
      for (int kt = 0; kt < 32; ++kt) {
        short8v ah[4], bh[4];
#pragma unroll
        for (int bt = 0; bt < 4; ++bt)
          ah[bt] = xh[((size_t)(tt * 32 + kt) * 4 + bt) * 64 + l];
#pragma unroll
        for (int q = 0; q < 4; ++q)
          bh[q] = wh[((size_t)(nt0 + q) * 32 + kt) * 64 + l];
#pragma unroll
        for (int bt = 0; bt < 4; ++bt)
#pragma unroll
          for (int q = 0; q < 4; ++q)
            acc[bt][q] = __builtin_amdgcn_mfma_f32_16x16x32_bf16(ah[bt], bh[q], acc[bt][q], 0, 0, 0);
      }

#pragma unroll
      for (int q = 0; q < 4; ++q) {
        const int n = (nt0 + q) * 16 + (l & 15);
        const int g = n >> 10;
        const int cb = (n & 1023) >> 2;
        const int c = n & 3;
        const float bv = bias[n];
#pragma unroll
        for (int bt = 0; bt < 4; ++bt)
#pragma unroll
          for (int r = 0; r < 4; ++r) {
            const int b = bt * 16 + (l >> 4) * 4 + r;
            llc_store1(gx + (((size_t)tt * 256 + cb) * 64 + b) * 16 + c * 4 + g,
                       acc[bt][q][r] + bv);
          }
      }
      asm volatile("s_waitcnt vmcnt(0)" ::: "memory");
      __syncthreads();
      if (tid == 0)
        __hip_atomic_fetch_add(&done[t0 + tt], 1u, __ATOMIC_RELAXED,
                               __HIP_MEMORY_SCOPE_AGENT);
    }
    return;
  }

  // ---------------- recurrence consumer role (bid < 128) ----------------
  short8v* wldsh = (short8v*)smemc;                    // [2][32][64] = 64 KB
  short8v* wldsl = wldsh + 4096;                       // 64 KB
  float* red = (float*)(wldsl + 4096);                 // 16 KB

  const int bt = w & 3;
  const int kt0 = (w >> 2) * 16;
  const int hbase = bid * 8;

  // stage Wh B-frags (2 coltiles x 32 kt), bf16 hi/lo (recurrent path keeps lo)
  for (int idx = tid; idx < 4096; idx += 512) {
    const int ct = idx >> 11;
    const int rem = idx & 2047;
    const int kt = rem >> 6;
    const int ll = rem & 63;
    const int cc = ll & 15;
    const int gc = ct * 16 + cc;
    const int c = gc >> 2, g = gc & 3;
    const int kb = kt * 32 + ((ll >> 4) << 3);
    short8v hi, lo;
#pragma unroll
    for (int j = 0; j < 8; ++j) {
      const float v = Wh[(size_t)(kb + j) * NG_ + g * H_ + hbase + c];
      const unsigned short bh = f2bf(v);
      hi[j] = (short)bh;
      lo[j] = (short)f2bf(v - bf2f(bh));
    }
    wldsh[idx] = hi;
    wldsl[idx] = lo;
  }

  const int eb = tid >> 3;        // output b
  const int c8 = tid & 7;         // output h-col within block
  const int hcol = hbase + c8;
  const size_t sOff = (((size_t)((hcol >> 5) * 4 + (eb >> 4)) * 64 +
                        ((((hcol & 31) >> 3) << 4) | (eb & 15))) * 8 + (hcol & 7));
  const int cbq = bid * 2 + (c8 >> 2);       // gx col-block
  const int ebt = eb >> 4;
  const int erb = eb & 15;
  const int err_ = erb & 3;
  const int elrow = (erb >> 2) << 4;
  const int ect = c8 >> 2;

  float c_reg = c_state[eb * H_ + hcol];

  if (tid == 0) {   // wait for this chunk's first gx slice
    while (__hip_atomic_load(&done[t0], __ATOMIC_RELAXED, __HIP_MEMORY_SCOPE_AGENT) < 8u)
      __builtin_amdgcn_s_sleep(1);
  }
  __syncthreads();

  for (int tt = 0; tt < tc; ++tt) {
    const int t = t0 + tt;
    const unsigned short* __restrict__ hf_in = (t & 1) ? hfB : hfA;
    unsigned short* __restrict__ hf_out = (t & 1) ? hfA : hfB;

    // 17 sc loads: gxv first, then 16 A-frags
    float4 gxv = llc_load4(gx + (((size_t)tt * 256 + cbq) * 64 + eb) * 16 + (c8 & 3) * 4);
    float4 aq[16];
#pragma unroll
    for (int q = 0; q < 16; ++q)
      aq[q] = llc_load4((const float*)(hf_in + (((size_t)(kt0 + q) * 4 + bt) * 64 + l) * 8));

    f32x4 acc0 = (f32x4){0.f, 0.f, 0.f, 0.f};
    f32x4 acc1 = (f32x4){0.f, 0.f, 0.f, 0.f};

#define STEPQ(Q, VM)                                                        \
    { const short8v bh0 = wldsh[(kt0 + (Q)) * 64 + l];                      \
      const short8v bl0 = wldsl[(kt0 + (Q)) * 64 + l];                      \
      const short8v bh1 = wldsh[2048 + (kt0 + (Q)) * 64 + l];               \
      const short8v bl1 = wldsl[2048 + (kt0 + (Q)) * 64 + l];               \
      VMWAIT(VM)                                                            \
      const short8v av = __builtin_bit_cast(short8v, aq[Q]);                \
      acc0 = __builtin_amdgcn_mfma_f32_16x16x32_bf16(av, bh0, acc0, 0, 0, 0); \
      acc0 = __builtin_amdgcn_mfma_f32_16x16x32_bf16(av, bl0, acc0, 0, 0, 0); \
      acc1 = __builtin_amdgcn_mfma_f32_16x16x32_bf16(av, bh1, acc1, 0, 0, 0); \
      acc1 = __builtin_amdgcn_mfma_f32_16x16x32_bf16(av, bl1, acc1, 0, 0, 0); }
    STEPQ(0, 15)  STEPQ(1, 14)  STEPQ(2, 13)  STEPQ(3, 12)
    STEPQ(4, 11)  STEPQ(5, 10)  STEPQ(6, 9)   STEPQ(7, 8)
    STEPQ(8, 7)   STEPQ(9, 6)   STEPQ(10, 5)  STEPQ(11, 4)
    STEPQ(12, 3)  STEPQ(13, 2)  STEPQ(14, 1)  STEPQ(15, 0)
#undef STEPQ

#pragma unroll
    for (int r = 0; r < 4; ++r) {
      red[((w * 2 + 0) * 64 + l) * 4 + r] = acc0[r];
      red[((w * 2 + 1) * 64 + l) * 4 + r] = acc1[r];
    }
    __syncthreads();

    float hn_save;
    {
      const float* gp = &gxv.x;
      float v[4];
#pragma unroll
      for (int g = 0; g < 4; ++g) {
        const int cc = (c8 & 3) * 4 + g;
        const int lp = elrow | cc;
        v[g] = gp[g] +
               red[(((0 * 4 + ebt) * 2 + ect) * 64 + lp) * 4 + err_] +
               red[(((1 * 4 + ebt) * 2 + ect) * 64 + lp) * 4 + err_];
      }
      const float si = fsigmoid(v[0]);
      const float sf = fsigmoid(v[1]);
      const float gt = ftanh(v[2]);
      const float so = fsigmoid(v[3]);
      const float cn = sf * c_reg + si * gt;
      const float hn = so * ftanh(cn);
      c_reg = cn;
      hn_save = hn;
      llc_store_u16(hf_out + sOff, (unsigned)f2bf(hn));   // the only pre-barrier store
    }

    // drain h handoff store, then leader-epoch barrier (R14 style):
    // 127 blocks poll ONE read-shared epoch cell; only bid 0 sweeps arrivals.
    asm volatile("s_waitcnt vmcnt(0)" ::: "memory");
    __syncthreads();
    if (tid == 0) {
      __hip_atomic_fetch_add(&bar[(bid & 7) << 5], 1u,
                             __ATOMIC_RELAXED, __HIP_MEMORY_SCOPE_AGENT);
    }
    // deferred output store (consumer-private, nothing polls it)
    ys[(size_t)eb * (T_ * H_) + (size_t)t * H_ + hcol] = hn_save;
    if (tid == 0) {
      const unsigned tgt = (unsigned)(t + 1);
      if (bid == 0) {
        unsigned s;
        do {
          s = 0;
#pragma unroll
          for (int i = 0; i < 8; ++i)
            s += __hip_atomic_load(&bar[i << 5], __ATOMIC_RELAXED,
                                   __HIP_MEMORY_SCOPE_AGENT);
          if (s < 128u * tgt) __builtin_amdgcn_s_sleep(1);
        } while (s < 128u * tgt);
        __hip_atomic_store(&bar[256], tgt, __ATOMIC_RELAXED,
                           __HIP_MEMORY_SCOPE_AGENT);
      } else {
        while (__hip_atomic_load(&bar[256], __ATOMIC_RELAXED,
                                 __HIP_MEMORY_SCOPE_AGENT) < tgt)
          __builtin_amdgcn_s_sleep(1);
      }
    }
    if (tid == 64 && tt + 1 < tc) {   // parallel: ensure next gx slice published
      while (__hip_atomic_load(&done[t + 1], __ATOMIC_RELAXED,
                               __HIP_MEMORY_SCOPE_AGENT) < 8u)
        __builtin_amdgcn_s_sleep(1);
    }
    __syncthreads();
  }

  c_state[eb * H_ + hcol] = c_reg;
}

// ---------------- fallback: fused step (tiny ws) ----------------
#define FMA16F(V, W0, W1, W2, W3)               \
  acc[0][0] = fmaf((V), (W0).x, acc[0][0]);     \
  acc[1][0] = fmaf((V), (W0).y, acc[1][0]);     \
  acc[2][0] = fmaf((V), (W0).z, acc[2][0]);     \
  acc[3][0] = fmaf((V), (W0).w, acc[3][0]);     \
  acc[0][1] = fmaf((V), (W1).x, acc[0][1]);     \
  acc[1][1] = fmaf((V), (W1).y, acc[1][1]);     \
  acc[2][1] = fmaf((V), (W1).z, acc[2][1]);     \
  acc[3][1] = fmaf((V), (W1).w, acc[3][1]);     \
  acc[0][2] = fmaf((V), (W2).x, acc[0][2]);     \
  acc[1][2] = fmaf((V), (W2).y, acc[1][2]);     \
  acc[2][2] = fmaf((V), (W2).z, acc[2][2]);     \
  acc[3][2] = fmaf((V), (W2).w, acc[3][2]);     \
  acc[0][3] = fmaf((V), (W3).x, acc[0][3]);     \
  acc[1][3] = fmaf((V), (W3).y, acc[1][3]);     \
  acc[2][3] = fmaf((V), (W3).z, acc[2][3]);     \
  acc[3][3] = fmaf((V), (W3).w, acc[3][3]);

__global__ __launch_bounds__(512, 2) void k_lstm_step_fused(
    const float* __restrict__ xsrc, const float* __restrict__ Wi,
    const float* __restrict__ Wh, const float* __restrict__ bias,
    const float* __restrict__ hT_in, float* __restrict__ hT_out,
    float* __restrict__ c_state, float* __restrict__ ys_t) {
  __shared__ float red[8 * 64 * 17];
  const int tid = threadIdx.x;
  const int lane = tid & 63;
  const int w = tid >> 6;
  const int hbase = blockIdx.x * 4;
  float acc[4][4];
#pragma unroll
  for (int c = 0; c < 4; ++c)
#pragma unroll
    for (int g = 0; g < 4; ++g) acc[c][g] = 0.f;
  const int k0 = w * 128;
#pragma unroll 2
  for (int k = k0; k < k0 + 128; ++k) {
    const float hv = hT_in[k * 64 + lane];
    const float xv = xsrc[(size_t)lane * (T_ * D_) + k];
    const float4 wh0 = *(const float4*)(Wh + (size_t)k * NG_ + 0 * H_ + hbase);
    const float4 wh1 = *(const float4*)(Wh + (size_t)k * NG_ + 1 * H_ + hbase);
    const float4 wh2 = *(const float4*)(Wh + (size_t)k * NG_ + 2 * H_ + hbase);
    const float4 wh3 = *(const float4*)(Wh + (size_t)k * NG_ + 3 * H_ + hbase);
    FMA16F(hv, wh0, wh1, wh2, wh3)
    const float4 wi0 = *(const float4*)(Wi + (size_t)k * NG_ + 0 * H_ + hbase);
    const float4 wi1 = *(const float4*)(Wi + (size_t)k * NG_ + 1 * H_ + hbase);
    const float4 wi2 = *(const float4*)(Wi + (size_t)k * NG_ + 2 * H_ + hbase);
    const float4 wi3 = *(const float4*)(Wi + (size_t)k * NG_ + 3 * H_ + hbase);
    FMA16F(xv, wi0, wi1, wi2, wi3)
  }
#pragma unroll
  for (int c = 0; c < 4; ++c)
#pragma unroll
    for (int g = 0; g < 4; ++g) red[(w * 64 + lane) * 17 + c * 4 + g] = acc[c][g];
  __syncthreads();
  if (tid < 256) {
    const int b = tid >> 2;
    const int c = tid & 3;
    const int h = hbase + c;
    float v[4];
#pragma unroll
    for (int g = 0; g < 4; ++g) {
      float s = bias[g * H_ + h];
#pragma unroll
      for (int ww = 0; ww < 8; ++ww) s += red[(ww * 64 + b) * 17 + c * 4 + g];
      v[g] = s;
    }
    const float cold = c_state[b * H_ + h];
    const float si = 1.f / (1.f + expf(-v[0]));
    const float sf = 1.f / (1.f + expf(-v[1]));
    const float gt = tanhf(v[2]);
    const float so = 1.f / (1.f + expf(-v[3]));
    const float cn = sf * cold + si * gt;
    const float hn = so * tanhf(cn);
    c_state[b * H_ + h] = cn;
    hT_out[h * 64 + b] = hn;
    ys_t[(size_t)b * (T_ * H_) + h] = hn;
  }
}

extern "C" void kernel_launch(void* const* d_in, const int* in_sizes, int n_in,
                              void* d_out, int out_size, void* d_ws, size_t ws_size,
                              hipStream_t stream) {
  const float* c0   = (const float*)d_in[0];
  const float* h0   = (const float*)d_in[1];
  const float* x    = (const float*)d_in[2];
  const float* Wi   = (const float*)d_in[3];
  const float* Wh   = (const float*)d_in[4];
  const float* bias = (const float*)d_in[5];

  float* out     = (float*)d_out;
  float* c_state = out;
  float* h_final = out + B_ * H_;
  float* ys      = out + 2 * B_ * H_;

  const size_t hbytes = (size_t)B_ * H_ * sizeof(float);   // 256 KB
  char* ws = (char*)d_ws;
  unsigned* bar = (unsigned*)ws;                        // 8 KB (cells+epoch+done[512])
  char* hbufA = ws + 8192;                              // 256 KB slot
  char* hbufB = hbufA + hbytes;
  const size_t wfrag_n = (size_t)256 * 32 * 64;         // 524288 frags
  short8v* wh = (short8v*)(hbufB + hbytes);             // 8 MB (hi only)
  char* chunkbase = (char*)(wh + wfrag_n);

  const size_t xfrag_t = (size_t)32 * 4 * 64;           // frags per t
  const size_t per_t = xfrag_t * sizeof(short8v) + (size_t)256 * 64 * 16 * sizeof(float);
  const size_t fixed = (size_t)(chunkbase - ws);
  size_t avail = (ws_size > fixed) ? ws_size - fixed : 0;
  int Tc = (int)(avail / per_t);
  if (Tc > T_) Tc = T_;

  hipMemsetAsync(bar, 0, 8192, stream);
  hipMemcpyAsync(c_state, c0, hbytes, hipMemcpyDeviceToDevice, stream);

  if (Tc >= 1) {
    unsigned short* hfA = (unsigned short*)hbufA;
    unsigned short* hfB = (unsigned short*)hbufB;

    k_init_hfrag<<<256, 256, 0, stream>>>(h0, hfA);
    k_prep_w<<<2048, 256, 0, stream>>>(Wi, wh);

    const unsigned smem = (4096 + 4096) * 16 + 4096 * 4;   // 147456 B

    for (int t0 = 0; t0 < T_; t0 += Tc) {
      const int tc = (T_ - t0 < Tc) ? (T_ - t0) : Tc;
      short8v* xh = (short8v*)chunkbase;
      float* gxbuf = (float*)(xh + (size_t)tc * xfrag_t);

      k_prep_x<<<tc * 32, 256, 0, stream>>>(x, xh, t0);

      int t0v = t0, tcv = tc;
      void* args[] = {(void*)&Wh,  (void*)&xh,   (void*)&wh,
                      (void*)&bias, (void*)&gxbuf,
                      (void*)&hfA, (void*)&hfB,  (void*)&c_state,
                      (void*)&ys,  (void*)&bar,  (void*)&t0v, (void*)&tcv};
      hipLaunchCooperativeKernel((void*)k_fused, dim3(256), dim3(512), args,
                                 smem, stream);
    }
    k_h_final<<<256, 256, 0, stream>>>(ys, h_final);
  } else {
    float* hA = (float*)hbufA;
    float* hB = (float*)hbufB;
    k_trans_h_fwd<<<B_ * H_ / 256, 256, 0, stream>>>(h0, hA);
    for (int t = 0; t < T_; ++t) {
      const float* hin = (t & 1) ? hB : hA;
      float* hout      = (t & 1) ? hA : hB;
      k_lstm_step_fused<<<256, 512, 0, stream>>>(
          x + (size_t)t * D_, Wi, Wh, bias, hin, hout, c_state,
          ys + (size_t)t * H_);
    }
    k_trans_h_back<<<B_ * H_ / 256, 256, 0, stream>>>(hA, h_final);
  }
}